// Round 1
// baseline (289.511 us; speedup 1.0000x reference)
//
#include <hip/hip_runtime.h>

// Shift op: out[n, c*9 + s, h, w] = x_pad[n, c, h + s/3, w + s%3]
// with pad=1 zero padding. x: (32, 64, 56, 56) fp32 -> out: (32, 576, 56, 56).
//
// Memory-bound (write-dominated: 231 MB out vs 25.7 MB in). Strategy:
// one thread per output float4 (W=56 -> 14 float4 per row, aligned),
// scalar input loads (unaligned due to dx shift; served by L1/L2),
// vector float4 stores for full write coalescing.

#define N_ 32
#define C_ 64
#define H_ 56
#define W_ 56
#define KK 9
#define W4 (W_ / 4)                    // 14 float4 per row
#define ROW_F4 W4                      // float4s per (n, oc, h) row
#define OUT_F4 (N_ * C_ * KK * H_ * W4)  // total output float4s

__global__ __launch_bounds__(256) void shift_kernel(const float* __restrict__ x,
                                                    float4* __restrict__ out) {
    int idx = blockIdx.x * blockDim.x + threadIdx.x;
    if (idx >= OUT_F4) return;

    // Decompose: idx = (((n*C_ + c)*KK + s)*H_ + h)*W4 + w4
    int w4 = idx % W4;
    int t  = idx / W4;
    int h  = t % H_;
    t /= H_;
    int s  = t % KK;
    t /= KK;
    int c  = t % C_;
    int n  = t / C_;

    int dy = s / 3 - 1;   // -1, 0, 1
    int dx = s % 3 - 1;   // -1, 0, 1

    int ih = h + dy;

    float4 v;
    if (ih < 0 || ih >= H_) {
        v = make_float4(0.f, 0.f, 0.f, 0.f);
    } else {
        const float* row = x + (((long)(n * C_ + c) * H_) + ih) * W_;
        int w0 = w4 * 4 + dx;
        if (w4 > 0 && w4 < W4 - 1) {
            // interior: w0..w0+3 all in [0, W_)
            v.x = row[w0];
            v.y = row[w0 + 1];
            v.z = row[w0 + 2];
            v.w = row[w0 + 3];
        } else {
            int w1 = w0 + 1, w2 = w0 + 2, w3 = w0 + 3;
            v.x = (w0 >= 0 && w0 < W_) ? row[w0] : 0.f;
            v.y = (w1 >= 0 && w1 < W_) ? row[w1] : 0.f;
            v.z = (w2 >= 0 && w2 < W_) ? row[w2] : 0.f;
            v.w = (w3 >= 0 && w3 < W_) ? row[w3] : 0.f;
        }
    }
    out[idx] = v;
}

extern "C" void kernel_launch(void* const* d_in, const int* in_sizes, int n_in,
                              void* d_out, int out_size, void* d_ws, size_t ws_size,
                              hipStream_t stream) {
    const float* x = (const float*)d_in[0];
    float4* out = (float4*)d_out;

    int total = OUT_F4;
    int block = 256;
    int grid = (total + block - 1) / block;
    shift_kernel<<<grid, block, 0, stream>>>(x, out);
}

// Round 3
// 242.865 us; speedup vs baseline: 1.1921x; 1.1921x over previous
//
#include <hip/hip_runtime.h>

// Shift op: out[n, c*9 + s, h, w] = x_pad[n, c, h + s/3, w + s%3], pad=1.
// x: (32, 64, 56, 56) fp32 -> out: (32, 576, 56, 56).
//
// Write-BW-bound (231 MB out, 25.7 MB in). Structure: one thread per INPUT
// (n,c,h,w4) float4 position. Each thread loads a 3x6 float window (aligned
// float4 + 2 edge scalars per row) and emits all 9 shifted output float4s
// via register selection + nontemporal coalesced dwordx4 stores.

#define N_ 32
#define C_ 64
#define H_ 56
#define W_ 56
#define W4 14                      // float4s per row
#define PLANE (H_ * W_)            // 3136 floats per (n,c) plane
#define POS_PER_PLANE (H_ * W4)    // 784
#define TOTAL (N_ * C_ * POS_PER_PLANE)  // 1,605,632 threads

typedef float f4 __attribute__((ext_vector_type(4)));

__global__ __launch_bounds__(256) void shift_kernel(const float* __restrict__ x,
                                                    float* __restrict__ out) {
    int t = blockIdx.x * blockDim.x + threadIdx.x;
    if (t >= TOTAL) return;

    int w4 = t % W4;
    int r  = t / W4;
    int h  = r % H_;
    int nc = r / H_;

    int w0 = w4 * 4;
    const float* plane = x + (long)nc * PLANE;

    // rowbuf[d][j] = x[nc, h+d-1, w0-1+j] (zero-padded), j in [0,6)
    float rowbuf[3][6];
#pragma unroll
    for (int d = 0; d < 3; ++d) {
        int ih = h + d - 1;
        if (ih < 0 || ih >= H_) {
#pragma unroll
            for (int j = 0; j < 6; ++j) rowbuf[d][j] = 0.f;
        } else {
            const float* rp = plane + ih * W_;
            f4 v = *(const f4*)(rp + w0);   // aligned 16B load
            rowbuf[d][1] = v.x;
            rowbuf[d][2] = v.y;
            rowbuf[d][3] = v.z;
            rowbuf[d][4] = v.w;
            rowbuf[d][0] = (w4 > 0)      ? rp[w0 - 1] : 0.f;
            rowbuf[d][5] = (w4 < W4 - 1) ? rp[w0 + 4] : 0.f;
        }
    }

    // out flat index for (nc, s, h, w0): ((nc*9 + s)*H_ + h)*W_ + w0
    float* ob = out + ((long)(nc * 9) * H_ + h) * W_ + w0;
#pragma unroll
    for (int dy = 0; dy < 3; ++dy) {
#pragma unroll
        for (int dx = 0; dx < 3; ++dx) {
            f4 v = { rowbuf[dy][dx],     rowbuf[dy][dx + 1],
                     rowbuf[dy][dx + 2], rowbuf[dy][dx + 3] };
            f4* dst = (f4*)(ob + (long)(dy * 3 + dx) * PLANE);
            __builtin_nontemporal_store(v, dst);
        }
    }
}

extern "C" void kernel_launch(void* const* d_in, const int* in_sizes, int n_in,
                              void* d_out, int out_size, void* d_ws, size_t ws_size,
                              hipStream_t stream) {
    const float* x = (const float*)d_in[0];
    float* out = (float*)d_out;

    int block = 256;
    int grid = (TOTAL + block - 1) / block;   // 6272 blocks exactly
    shift_kernel<<<grid, block, 0, stream>>>(x, out);
}